// Round 8
// baseline (27.246 us; speedup 1.0000x reference)
//
#include <hip/hip_runtime.h>

// RegionAttention: bin 8M landmarks into a 512x512 grid; out[i] = enhanced[i]
// if any landmark falls in bin i else 1.0f.
//
// Round 8: replace the 256-private-region dump (8 MB store + 8 MB dirty-L2
// writeback at the dispatch boundary + 8 MB merge re-read) with device-scope
// global_atomic_or into 32 shared masks (1 MB). Attacks the three remaining
// modeled slack terms at once; bin streaming body is byte-identical to R5/R7.
// Ledger: occupancy(R4) null, MLP(R5) null, coop-fusion(R6) negative,
// merge-width(R7) null.

#define N_LANDMARKS 8388608
#define N_BINS      262144            // 512*512
#define GRID_COLS   512
#define NWORDS      (N_BINS / 32)     // 8192 dwords = 32 KB bitmask
#define NQWORDS     (NWORDS / 2)      // 4096 qwords per mask
#define NMASKS      32                // shared global masks (1 MB total)
#define P1_BLOCKS   256
#define P1_THREADS  1024
#define P1_ITERS    16                // (N_LANDMARKS/2) / (P1_BLOCKS*P1_THREADS)

// --- pass 1: LDS bitmask, then atomic-OR dump into shared mask ---------------

__global__ __launch_bounds__(P1_THREADS)
void bin_atomic_kernel(const float4* __restrict__ lm2,
                       unsigned long long* __restrict__ gmask) { // [NMASKS][NQWORDS]
    __shared__ unsigned int mask[NWORDS];
    const int tid = threadIdx.x;

    uint4* mask4 = (uint4*)mask;
    #pragma unroll
    for (int w = tid; w < NWORDS / 4; w += P1_THREADS)
        mask4[w] = make_uint4(0u, 0u, 0u, 0u);
    __syncthreads();

    const int total = P1_BLOCKS * P1_THREADS;          // 262144 threads
    const int base  = blockIdx.x * P1_THREADS + tid;

    float4 buf[P1_ITERS];
    #pragma unroll
    for (int k = 0; k < P1_ITERS; ++k)
        buf[k] = lm2[base + k * total];

    #pragma unroll
    for (int k = 0; k < P1_ITERS; ++k) {
        float4 v = buf[k];                             // (x0,y0,x1,y1)
        int c0 = min((int)(v.x * 0.0625f), GRID_COLS - 1);
        int r0 = min((int)(v.y * 0.0625f), GRID_COLS - 1);
        int c1 = min((int)(v.z * 0.0625f), GRID_COLS - 1);
        int r1 = min((int)(v.w * 0.0625f), GRID_COLS - 1);
        unsigned int i0 = (unsigned int)(r0 * GRID_COLS + c0);
        unsigned int i1 = (unsigned int)(r1 * GRID_COLS + c1);
        atomicOr(&mask[i0 >> 5], 1u << (i0 & 31));     // ds_or_b32, no return
        atomicOr(&mask[i1 >> 5], 1u << (i1 & 31));
    }
    __syncthreads();

    // dump: 4 qword-atomics per thread, wave-contiguous (512 B per wave-op).
    unsigned long long* dst =
        gmask + (size_t)(blockIdx.x & (NMASKS - 1)) * NQWORDS;
    const unsigned long long* src = (const unsigned long long*)mask;
    #pragma unroll
    for (int q = tid; q < NQWORDS; q += P1_THREADS)
        atomicOr(&dst[q], src[q]);
}

// --- pass 2: OR the 32 masks, blend ------------------------------------------
// 65536 threads; thread t owns float4 t (4 bins). Word = t>>3 (8 lanes share,
// 32B/wave-load, L2-hot 1 MB footprint); nibble select by t&7.

__global__ __launch_bounds__(256)
void merge_blend_kernel(const unsigned int* __restrict__ gmaskW,
                        const float4* __restrict__ ew4,
                        float4* __restrict__ out4) {
    const int t = blockIdx.x * 256 + threadIdx.x;      // 0..65535
    const int w = t >> 3;                              // word index 0..8191

    unsigned int m = 0u;
    #pragma unroll
    for (int s = 0; s < NMASKS; ++s)
        m |= gmaskW[s * NWORDS + w];

    const int sh = (t & 7) * 4;
    float4 e = ew4[t];
    float4 r;
    r.x = ((m >> (sh + 0)) & 1u) ? e.x : 1.0f;
    r.y = ((m >> (sh + 1)) & 1u) ? e.y : 1.0f;
    r.z = ((m >> (sh + 2)) & 1u) ? e.z : 1.0f;
    r.w = ((m >> (sh + 3)) & 1u) ? e.w : 1.0f;
    out4[t] = r;
}

// --- fallback (small ws): byte-flag path --------------------------------------

__global__ void scatter_flags_kernel(const float4* __restrict__ lm2,
                                     unsigned char* __restrict__ flags, int n4) {
    int i = blockIdx.x * blockDim.x + threadIdx.x;
    const int stride = gridDim.x * blockDim.x;
    for (; i < n4; i += stride) {
        float4 v = lm2[i];
        int c0 = min((int)(v.x * 0.0625f), GRID_COLS - 1);
        int r0 = min((int)(v.y * 0.0625f), GRID_COLS - 1);
        int c1 = min((int)(v.z * 0.0625f), GRID_COLS - 1);
        int r1 = min((int)(v.w * 0.0625f), GRID_COLS - 1);
        flags[r0 * GRID_COLS + c0] = (unsigned char)1;
        flags[r1 * GRID_COLS + c1] = (unsigned char)1;
    }
}

__global__ void blend_kernel(const unsigned char* __restrict__ flags,
                             const float* __restrict__ ew,
                             float* __restrict__ out) {
    int i = blockIdx.x * blockDim.x + threadIdx.x;
    out[i] = flags[i] ? ew[i] : 1.0f;
}

extern "C" void kernel_launch(void* const* d_in, const int* in_sizes, int n_in,
                              void* d_out, int out_size, void* d_ws, size_t ws_size,
                              hipStream_t stream) {
    const float4* lm2 = (const float4*)d_in[0];
    const float*  ew  = (const float*)d_in[1];
    float* out        = (float*)d_out;

    const size_t gmask_bytes = (size_t)NMASKS * NWORDS * sizeof(unsigned int); // 1 MB

    if (ws_size >= gmask_bytes) {
        unsigned long long* gmask = (unsigned long long*)d_ws;
        hipMemsetAsync(gmask, 0, gmask_bytes, stream);
        bin_atomic_kernel<<<P1_BLOCKS, P1_THREADS, 0, stream>>>(lm2, gmask);
        merge_blend_kernel<<<N_BINS / 4 / 256, 256, 0, stream>>>(
            (const unsigned int*)gmask, (const float4*)ew, (float4*)out);
    } else {
        unsigned char* flags = (unsigned char*)d_ws;
        hipMemsetAsync(flags, 0, N_BINS, stream);
        scatter_flags_kernel<<<2048, 256, 0, stream>>>(lm2, flags, N_LANDMARKS / 2);
        blend_kernel<<<N_BINS / 256, 256, 0, stream>>>(flags, ew, out);
    }
}